// Round 5
// baseline (1379.915 us; speedup 1.0000x reference)
//
#include <hip/hip_runtime.h>
#include <hip/hip_bf16.h>
#include <hip/hip_fp16.h>

#define B_SZ 64
#define T_SZ 2048
#define I_SZ 128
#define H_SZ 256
#define O_SZ 128

typedef _Float16 half_t;
typedef _Float16 h2_t __attribute__((ext_vector_type(2)));
typedef __fp16   fp16x2_t __attribute__((ext_vector_type(2)));
typedef _Float16 h8_t __attribute__((ext_vector_type(8)));
typedef float    f4_t __attribute__((ext_vector_type(4)));

static __device__ __forceinline__ h2_t uint_as_h2(unsigned u) {
  union { unsigned u; h2_t h; } x; x.u = u; return x.h;
}
static __device__ __forceinline__ unsigned pack_h2(float a, float b) {
#if __has_builtin(__builtin_amdgcn_cvt_pkrtz)
  union { fp16x2_t h; unsigned u; } x;
  x.h = __builtin_amdgcn_cvt_pkrtz(a, b);  // one v_cvt_pkrtz_f16_f32
  return x.u;
#else
  h2_t h; h[0] = (_Float16)a; h[1] = (_Float16)b;
  union { h2_t h; unsigned u; } x2; x2.h = h; return x2.u;
#endif
}
static __device__ __forceinline__ float dot2(h2_t a, h2_t b, float c) {
#if __has_builtin(__builtin_amdgcn_fdot2)
  return __builtin_amdgcn_fdot2(a, b, c, false);
#else
  return c + (float)a[0] * (float)b[0] + (float)a[1] * (float)b[1];
#endif
}
static __device__ __forceinline__ float fast_rcp(float x) {
#if __has_builtin(__builtin_amdgcn_rcpf)
  return __builtin_amdgcn_rcpf(x);
#else
  return 1.0f / x;
#endif
}

// ---------------------------------------------------------------------------
// TN GEMM with bias:  C[m,n] = sum_k A[m,k] * Bw[n,k] + bias[n]
// A: fp32 or f16 row-major (M, KTOT); Bw: fp32 row-major (N, KTOT)
// Out: f16 or fp32 row-major (M, ldo). MFMA 16x16x32 f16, XOR-swizzled LDS.
// ---------------------------------------------------------------------------
template <int BM, int BN, int BK, int KTOT, bool A_HALF, bool OUT_HALF>
__global__ __launch_bounds__(256, 2) void gemm_tn_bias(
    const void* __restrict__ Ap, const float* __restrict__ Bw,
    const float* __restrict__ bias, void* __restrict__ Out, int ldo) {
  extern __shared__ half_t lds[];
  half_t* As = lds;                 // [BM][BK] swizzled
  half_t* Bs = lds + BM * BK;       // [BN][BK] swizzled

  const int tid = threadIdx.x;
  const long row0 = (long)blockIdx.x * BM;
  const int col0 = blockIdx.y * BN;

  constexpr int MI = 4;
  constexpr int NJ = (BN / 2) / 16;
  const int lane = tid & 63, wid = tid >> 6;
  const int wm = (wid >> 1) * 64;
  const int wn = (wid & 1) * (BN / 2);

  f4_t acc[MI][NJ];
#pragma unroll
  for (int mi = 0; mi < MI; ++mi)
#pragma unroll
    for (int nj = 0; nj < NJ; ++nj) acc[mi][nj] = (f4_t){0.f, 0.f, 0.f, 0.f};

#pragma unroll 1
  for (int kt = 0; kt < KTOT / BK; ++kt) {
    if (kt) __syncthreads();
    constexpr int AIT = (BM * BK) / (256 * 8);
#pragma unroll
    for (int it = 0; it < AIT; ++it) {
      int idx = (it * 256 + tid) * 8;
      int r = idx / BK, c = idx % BK;
      uint4 v;
      if (A_HALF) {
        v = *(const uint4*)((const half_t*)Ap + (row0 + r) * (long)KTOT +
                            kt * BK + c);
      } else {
        const float* src =
            (const float*)Ap + (row0 + r) * (long)KTOT + kt * BK + c;
        float4 f0 = *(const float4*)(src);
        float4 f1 = *(const float4*)(src + 4);
        v.x = pack_h2(f0.x, f0.y); v.y = pack_h2(f0.z, f0.w);
        v.z = pack_h2(f1.x, f1.y); v.w = pack_h2(f1.z, f1.w);
      }
      int chunk = (c >> 3) ^ (r & 7);
      *(uint4*)(&As[r * BK + chunk * 8]) = v;
    }
    constexpr int BIT = (BN * BK) / (256 * 8);
#pragma unroll
    for (int it = 0; it < BIT; ++it) {
      int idx = (it * 256 + tid) * 8;
      int r = idx / BK, c = idx % BK;
      const float* src = Bw + (long)(col0 + r) * KTOT + kt * BK + c;
      float4 f0 = *(const float4*)(src);
      float4 f1 = *(const float4*)(src + 4);
      uint4 v;
      v.x = pack_h2(f0.x, f0.y); v.y = pack_h2(f0.z, f0.w);
      v.z = pack_h2(f1.x, f1.y); v.w = pack_h2(f1.z, f1.w);
      int chunk = (c >> 3) ^ (r & 7);
      *(uint4*)(&Bs[r * BK + chunk * 8]) = v;
    }
    __syncthreads();

#pragma unroll
    for (int ks = 0; ks < BK / 32; ++ks) {
      h8_t af[MI], bf[NJ];
#pragma unroll
      for (int mi = 0; mi < MI; ++mi) {
        int r = wm + mi * 16 + (lane & 15);
        int chunk = (ks * 4 + (lane >> 4)) ^ (r & 7);
        af[mi] = *(const h8_t*)(&As[r * BK + chunk * 8]);
      }
#pragma unroll
      for (int nj = 0; nj < NJ; ++nj) {
        int r = wn + nj * 16 + (lane & 15);
        int chunk = (ks * 4 + (lane >> 4)) ^ (r & 7);
        bf[nj] = *(const h8_t*)(&Bs[r * BK + chunk * 8]);
      }
#pragma unroll
      for (int mi = 0; mi < MI; ++mi)
#pragma unroll
        for (int nj = 0; nj < NJ; ++nj)
          acc[mi][nj] = __builtin_amdgcn_mfma_f32_16x16x32_f16(
              af[mi], bf[nj], acc[mi][nj], 0, 0, 0);
    }
  }

#pragma unroll
  for (int mi = 0; mi < MI; ++mi) {
#pragma unroll
    for (int nj = 0; nj < NJ; ++nj) {
#pragma unroll
      for (int e = 0; e < 4; ++e) {
        long row = row0 + wm + mi * 16 + (lane >> 4) * 4 + e;
        int col = col0 + wn + nj * 16 + (lane & 15);
        float val = acc[mi][nj][e] + bias[col];
        if (OUT_HALF)
          ((half_t*)Out)[row * ldo + col] = (half_t)val;
        else
          ((float*)Out)[row * ldo + col] = val;
      }
    }
  }
}

// ---------------------------------------------------------------------------
// Recurrent scan: one WG (512 threads = 8 waves = 2 waves/SIMD) per chain.
// wave w, lane l: output row = w*32+(l>>1), k-half = l&1 (128 k each).
// Adjacent lanes share an output row and split k -> the reduce is
// __shfl_xor(a,1) (intra-quad swizzle/DPP, cheap; no cross-half permute).
// x prefetched 8 steps deep in registers (8-step unrolled loop) so the
// ~900cy HBM stream latency is fully hidden; loads issued before the hs
// stores so in-order vmcnt keeps stores in flight.
// ---------------------------------------------------------------------------
__global__ __launch_bounds__(512, 1) void rnn_scan(
    const half_t* __restrict__ Xp,   // (B*T, H) f16 (aliases d_out)
    const float* __restrict__ Whh,   // (H, H) fp32
    const float* __restrict__ h0,    // (B, H) fp32
    half_t* __restrict__ Hs,         // (B*T, H) f16 (ws)
    float* __restrict__ hT) {        // (B, H) fp32 (d_out tail)
  __shared__ __align__(16) unsigned short hbuf[2][H_SZ];
  const int tid = threadIdx.x;
  const int b = blockIdx.x;
  const int lane = tid & 63;
  const int w = tid >> 6;
  const int out = w * 32 + (lane >> 1);
  const int kh = lane & 1;  // 0 or 1

  // This thread's weight half-row: Whh[out][kh*128 .. +128), packed f16.
  unsigned wpk[64];
  {
    const float* wrow = Whh + out * H_SZ + kh * 128;
#pragma unroll
    for (int i = 0; i < 32; ++i) {
      float4 f = *(const float4*)(wrow + i * 4);
      wpk[2 * i] = pack_h2(f.x, f.y);
      wpk[2 * i + 1] = pack_h2(f.z, f.w);
    }
  }
  if (tid < H_SZ) {
    union { _Float16 h; unsigned short s; } cv;
    cv.h = (_Float16)h0[b * H_SZ + tid];
    hbuf[0][tid] = cv.s;
  }
  __syncthreads();

  const unsigned short* xp =
      (const unsigned short*)(Xp + (long)b * T_SZ * H_SZ + out);
  half_t* hs = Hs + (long)b * T_SZ * H_SZ + out;
  const bool writer = (kh == 0);

  unsigned short xr[8];
#pragma unroll
  for (int j = 0; j < 8; ++j) xr[j] = xp[(long)j * H_SZ];

#pragma unroll 1
  for (int tc = 0; tc < T_SZ; tc += 8) {
    // Prefetch the NEXT 8 x-values (issued now, consumed 8 steps later).
    unsigned short xn[8];
    const bool more = (tc + 8 < T_SZ);
#pragma unroll
    for (int j = 0; j < 8; ++j)
      xn[j] = more ? xp[(long)(tc + 8 + j) * H_SZ] : (unsigned short)0;

#pragma unroll
    for (int j = 0; j < 8; ++j) {
      const int t = tc + j;
      const int cur = t & 1;
      const uint4* hp = (const uint4*)(&hbuf[cur][kh * 128]);
      float a0 = 0.f, a1 = 0.f, a2 = 0.f, a3 = 0.f;
#pragma unroll
      for (int i = 0; i < 16; ++i) {
        uint4 v = hp[i];
        a0 = dot2(uint_as_h2(wpk[4 * i + 0]), uint_as_h2(v.x), a0);
        a1 = dot2(uint_as_h2(wpk[4 * i + 1]), uint_as_h2(v.y), a1);
        a2 = dot2(uint_as_h2(wpk[4 * i + 2]), uint_as_h2(v.z), a2);
        a3 = dot2(uint_as_h2(wpk[4 * i + 3]), uint_as_h2(v.w), a3);
      }
      float a = (a0 + a1) + (a2 + a3);
      a += __shfl_xor(a, 1);  // combine the two k-halves (adjacent lanes)
      union { unsigned short s; _Float16 h; } xc; xc.s = xr[j];
      a += (float)xc.h;
      // tanh(a) = 1 - 2/(exp(2a)+1)  (saturates correctly)
      float ex = __expf(2.0f * a);
      float hn = 1.0f - 2.0f * fast_rcp(ex + 1.0f);

      if (writer) {
        union { _Float16 h; unsigned short s; } cv;
        cv.h = (_Float16)hn;
        hs[(long)t * H_SZ] = cv.h;
        hbuf[cur ^ 1][out] = cv.s;
        if (t == T_SZ - 1) hT[b * H_SZ + out] = hn;
      }
      __syncthreads();
    }
#pragma unroll
    for (int j = 0; j < 8; ++j) xr[j] = xn[j];
  }
}

extern "C" void kernel_launch(void* const* d_in, const int* in_sizes, int n_in,
                              void* d_out, int out_size, void* d_ws,
                              size_t ws_size, hipStream_t stream) {
  const float* x = (const float*)d_in[0];
  const float* h0 = (const float*)d_in[1];
  const float* Wxh = (const float*)d_in[2];
  const float* Whh = (const float*)d_in[3];
  const float* bh = (const float*)d_in[4];
  const float* Wout = (const float*)d_in[5];
  const float* bout = (const float*)d_in[6];

  // d_out: [0, 64MB) first holds f16 Xp scratch, finally Y fp32;
  // hT tail at element offset B*T*O is beyond the Xp region.
  half_t* Xp = (half_t*)d_out;
  half_t* Hs = (half_t*)d_ws;  // 64 MB
  float* Y = (float*)d_out;
  float* hT = (float*)d_out + (long)B_SZ * T_SZ * O_SZ;

  const long M = (long)B_SZ * T_SZ;  // 131072

  // Phase A: Xp = f16(x @ Wxh^T + bh)   M x 256, K=128
  {
    dim3 grid((unsigned)(M / 128), H_SZ / 128);
    size_t sh = 2ull * 128 * 128 * sizeof(half_t);  // 64 KB
    hipLaunchKernelGGL((gemm_tn_bias<128, 128, 128, 128, false, true>), grid,
                       dim3(256), sh, stream, (const void*)x, Wxh, bh,
                       (void*)Xp, H_SZ);
  }
  // Phase B: sequential scan, one WG (8 waves) per batch chain
  hipLaunchKernelGGL(rnn_scan, dim3(B_SZ), dim3(512), 0, stream, Xp, Whh, h0,
                     Hs, hT);
  // Phase C: Y = Hs @ Wout^T + bout   M x 128, K=256
  {
    dim3 grid((unsigned)(M / 128), O_SZ / 128);
    size_t sh = 2ull * 128 * 128 * sizeof(half_t);  // 64 KB
    hipLaunchKernelGGL((gemm_tn_bias<128, 128, 128, 256, true, false>), grid,
                       dim3(256), sh, stream, (const void*)Hs, Wout, bout,
                       (void*)Y, O_SZ);
  }
}

// Round 7
// 1147.618 us; speedup vs baseline: 1.2024x; 1.2024x over previous
//
#include <hip/hip_runtime.h>
#include <hip/hip_bf16.h>
#include <hip/hip_fp16.h>

#define B_SZ 64
#define T_SZ 2048
#define I_SZ 128
#define H_SZ 256
#define O_SZ 128

typedef _Float16 half_t;
typedef _Float16 h2_t __attribute__((ext_vector_type(2)));
typedef __fp16   fp16x2_t __attribute__((ext_vector_type(2)));
typedef _Float16 h8_t __attribute__((ext_vector_type(8)));
typedef float    f4_t __attribute__((ext_vector_type(4)));

static __device__ __forceinline__ h2_t uint_as_h2(unsigned u) {
  union { unsigned u; h2_t h; } x; x.u = u; return x.h;
}
static __device__ __forceinline__ unsigned pack_h2(float a, float b) {
#if __has_builtin(__builtin_amdgcn_cvt_pkrtz)
  union { fp16x2_t h; unsigned u; } x;
  x.h = __builtin_amdgcn_cvt_pkrtz(a, b);  // one v_cvt_pkrtz_f16_f32
  return x.u;
#else
  h2_t h; h[0] = (_Float16)a; h[1] = (_Float16)b;
  union { h2_t h; unsigned u; } x2; x2.h = h; return x2.u;
#endif
}
static __device__ __forceinline__ float dot2(h2_t a, h2_t b, float c) {
#if __has_builtin(__builtin_amdgcn_fdot2)
  return __builtin_amdgcn_fdot2(a, b, c, false);
#else
  return c + (float)a[0] * (float)b[0] + (float)a[1] * (float)b[1];
#endif
}
static __device__ __forceinline__ float fast_rcp(float x) {
#if __has_builtin(__builtin_amdgcn_rcpf)
  return __builtin_amdgcn_rcpf(x);
#else
  return 1.0f / x;
#endif
}

// DPP cross-lane adds on the VALU pipe (no LDS traffic).
// quad_perm codes: xor1 = [1,0,3,2] = 0xB1 ; xor2 = [2,3,0,1] = 0x4E.
static __device__ __forceinline__ float dpp_add_xor1(float x) {
#if __has_builtin(__builtin_amdgcn_mov_dpp)
  int y = __builtin_amdgcn_mov_dpp(__float_as_int(x), 0xB1, 0xF, 0xF, true);
  return x + __int_as_float(y);
#else
  return x + __shfl_xor(x, 1);
#endif
}
static __device__ __forceinline__ float dpp_add_xor2(float x) {
#if __has_builtin(__builtin_amdgcn_mov_dpp)
  int y = __builtin_amdgcn_mov_dpp(__float_as_int(x), 0x4E, 0xF, 0xF, true);
  return x + __int_as_float(y);
#else
  return x + __shfl_xor(x, 2);
#endif
}

// ---------------------------------------------------------------------------
// TN GEMM with bias:  C[m,n] = sum_k A[m,k] * Bw[n,k] + bias[n]
// ---------------------------------------------------------------------------
template <int BM, int BN, int BK, int KTOT, bool A_HALF, bool OUT_HALF>
__global__ __launch_bounds__(256, 2) void gemm_tn_bias(
    const void* __restrict__ Ap, const float* __restrict__ Bw,
    const float* __restrict__ bias, void* __restrict__ Out, int ldo) {
  extern __shared__ half_t lds[];
  half_t* As = lds;                 // [BM][BK] swizzled
  half_t* Bs = lds + BM * BK;       // [BN][BK] swizzled

  const int tid = threadIdx.x;
  const long row0 = (long)blockIdx.x * BM;
  const int col0 = blockIdx.y * BN;

  constexpr int MI = 4;
  constexpr int NJ = (BN / 2) / 16;
  const int lane = tid & 63, wid = tid >> 6;
  const int wm = (wid >> 1) * 64;
  const int wn = (wid & 1) * (BN / 2);

  f4_t acc[MI][NJ];
#pragma unroll
  for (int mi = 0; mi < MI; ++mi)
#pragma unroll
    for (int nj = 0; nj < NJ; ++nj) acc[mi][nj] = (f4_t){0.f, 0.f, 0.f, 0.f};

#pragma unroll 1
  for (int kt = 0; kt < KTOT / BK; ++kt) {
    if (kt) __syncthreads();
    constexpr int AIT = (BM * BK) / (256 * 8);
#pragma unroll
    for (int it = 0; it < AIT; ++it) {
      int idx = (it * 256 + tid) * 8;
      int r = idx / BK, c = idx % BK;
      uint4 v;
      if (A_HALF) {
        v = *(const uint4*)((const half_t*)Ap + (row0 + r) * (long)KTOT +
                            kt * BK + c);
      } else {
        const float* src =
            (const float*)Ap + (row0 + r) * (long)KTOT + kt * BK + c;
        float4 f0 = *(const float4*)(src);
        float4 f1 = *(const float4*)(src + 4);
        v.x = pack_h2(f0.x, f0.y); v.y = pack_h2(f0.z, f0.w);
        v.z = pack_h2(f1.x, f1.y); v.w = pack_h2(f1.z, f1.w);
      }
      int chunk = (c >> 3) ^ (r & 7);
      *(uint4*)(&As[r * BK + chunk * 8]) = v;
    }
    constexpr int BIT = (BN * BK) / (256 * 8);
#pragma unroll
    for (int it = 0; it < BIT; ++it) {
      int idx = (it * 256 + tid) * 8;
      int r = idx / BK, c = idx % BK;
      const float* src = Bw + (long)(col0 + r) * KTOT + kt * BK + c;
      float4 f0 = *(const float4*)(src);
      float4 f1 = *(const float4*)(src + 4);
      uint4 v;
      v.x = pack_h2(f0.x, f0.y); v.y = pack_h2(f0.z, f0.w);
      v.z = pack_h2(f1.x, f1.y); v.w = pack_h2(f1.z, f1.w);
      int chunk = (c >> 3) ^ (r & 7);
      *(uint4*)(&Bs[r * BK + chunk * 8]) = v;
    }
    __syncthreads();

#pragma unroll
    for (int ks = 0; ks < BK / 32; ++ks) {
      h8_t af[MI], bf[NJ];
#pragma unroll
      for (int mi = 0; mi < MI; ++mi) {
        int r = wm + mi * 16 + (lane & 15);
        int chunk = (ks * 4 + (lane >> 4)) ^ (r & 7);
        af[mi] = *(const h8_t*)(&As[r * BK + chunk * 8]);
      }
#pragma unroll
      for (int nj = 0; nj < NJ; ++nj) {
        int r = wn + nj * 16 + (lane & 15);
        int chunk = (ks * 4 + (lane >> 4)) ^ (r & 7);
        bf[nj] = *(const h8_t*)(&Bs[r * BK + chunk * 8]);
      }
#pragma unroll
      for (int mi = 0; mi < MI; ++mi)
#pragma unroll
        for (int nj = 0; nj < NJ; ++nj)
          acc[mi][nj] = __builtin_amdgcn_mfma_f32_16x16x32_f16(
              af[mi], bf[nj], acc[mi][nj], 0, 0, 0);
    }
  }

#pragma unroll
  for (int mi = 0; mi < MI; ++mi) {
#pragma unroll
    for (int nj = 0; nj < NJ; ++nj) {
#pragma unroll
      for (int e = 0; e < 4; ++e) {
        long row = row0 + wm + mi * 16 + (lane >> 4) * 4 + e;
        int col = col0 + wn + nj * 16 + (lane & 15);
        float val = acc[mi][nj][e] + bias[col];
        if (OUT_HALF)
          ((half_t*)Out)[row * ldo + col] = (half_t)val;
        else
          ((float*)Out)[row * ldo + col] = val;
      }
    }
  }
}

// ---------------------------------------------------------------------------
// Recurrent scan, phase-overlap redesign:
//   512 threads = 8 waves (2/SIMD). thread: g = tid>>3 (rows [4g,4g+4)),
//   q = lane&7 (k-chunk [32q,32q+32)).
//   * Each thread reads only 64 B of h (4x ds_read_b128), reused for 4 rows
//     -> LDS read instrs per CU per step: 128 -> 32.
//   * h stored with chunk stride 80 B: bank base 20q%32 covers all 8
//     multiples of 4 exactly once -> conflict-free 8-address broadcast.
//   * Reduce: xor1+xor2 on the VALU pipe via DPP quad_perm; only the final
//     xor4 touches the LDS pipe. Final row = 4g + 2*(q&1) + ((q>>1)&1);
//     lanes q and q^4 both hold it, q<4 writes.
//   * x prefetched 8 steps deep in registers.
// ---------------------------------------------------------------------------
__global__ __launch_bounds__(512, 1) void rnn_scan(
    const half_t* __restrict__ Xp,   // (B*T, H) f16 (aliases d_out)
    const float* __restrict__ Whh,   // (H, H) fp32
    const float* __restrict__ h0,    // (B, H) fp32
    half_t* __restrict__ Hs,         // (B*T, H) f16 (ws)
    float* __restrict__ hT) {        // (B, H) fp32 (d_out tail)
  __shared__ __align__(16) unsigned char hraw[2][8 * 80];  // 80B chunk stride
  const int tid = threadIdx.x;
  const int b = blockIdx.x;
  const int lane = tid & 63;
  const int q = lane & 7;                       // k-chunk id
  const int g = tid >> 3;                       // row group, rows [4g,4g+4)
  const int orow = 4 * g + 2 * (q & 1) + ((q >> 1) & 1);
  const bool writer = (q < 4);

  // Weights: 4 rows x 32 k, packed f16 -> 64 VGPRs.
  unsigned wpk[4][16];
#pragma unroll
  for (int r = 0; r < 4; ++r) {
    const float* wrow = Whh + (4 * g + r) * H_SZ + q * 32;
#pragma unroll
    for (int i = 0; i < 8; ++i) {
      float4 f = *(const float4*)(wrow + 4 * i);
      wpk[r][2 * i] = pack_h2(f.x, f.y);
      wpk[r][2 * i + 1] = pack_h2(f.z, f.w);
    }
  }
  if (tid < H_SZ) {
    union { _Float16 h; unsigned short s; } cv;
    cv.h = (_Float16)h0[b * H_SZ + tid];
    *(unsigned short*)&hraw[0][(tid >> 5) * 80 + (tid & 31) * 2] = cv.s;
  }
  __syncthreads();

  const unsigned short* xp =
      (const unsigned short*)(Xp + (long)b * T_SZ * H_SZ + orow);
  half_t* hs = Hs + (long)b * T_SZ * H_SZ + orow;
  const int hwr_off = (orow >> 5) * 80 + (orow & 31) * 2;
  const int hrd_off = q * 80;

  unsigned short xr[8];
#pragma unroll
  for (int j = 0; j < 8; ++j) xr[j] = xp[(long)j * H_SZ];

#pragma unroll 1
  for (int tc = 0; tc < T_SZ; tc += 8) {
    unsigned short xn[8];
    const bool more = (tc + 8 < T_SZ);
#pragma unroll
    for (int j = 0; j < 8; ++j)
      xn[j] = more ? xp[(long)(tc + 8 + j) * H_SZ] : (unsigned short)0;

#pragma unroll
    for (int j = 0; j < 8; ++j) {
      const int t = tc + j;
      const int cur = t & 1;
      const uint4* hp = (const uint4*)(&hraw[cur][hrd_off]);
      float a0 = 0.f, a1 = 0.f, a2 = 0.f, a3 = 0.f;
#pragma unroll
      for (int i = 0; i < 4; ++i) {
        uint4 v = hp[i];
#pragma unroll
        for (int c = 0; c < 4; ++c) {
          h2_t hh = uint_as_h2((&v.x)[c]);
          a0 = dot2(uint_as_h2(wpk[0][4 * i + c]), hh, a0);
          a1 = dot2(uint_as_h2(wpk[1][4 * i + c]), hh, a1);
          a2 = dot2(uint_as_h2(wpk[2][4 * i + c]), hh, a2);
          a3 = dot2(uint_as_h2(wpk[3][4 * i + c]), hh, a3);
        }
      }
      // reduce over 8 k-chunks: xor1+xor2 on VALU (DPP), xor4 via shuffle
      float s0 = dpp_add_xor1(a0), s1 = dpp_add_xor1(a1);
      float s2 = dpp_add_xor1(a2), s3 = dpp_add_xor1(a3);
      float u0 = (q & 1) ? s2 : s0;
      float u1 = (q & 1) ? s3 : s1;
      u0 = dpp_add_xor2(u0);
      u1 = dpp_add_xor2(u1);
      float z = (q & 2) ? u1 : u0;
      z += __shfl_xor(z, 4);

      union { unsigned short s; _Float16 h; } xc; xc.s = xr[j];
      z += (float)xc.h;
      // tanh(z) = 1 - 2/(exp(2z)+1)  (saturates correctly)
      float ex = __expf(2.0f * z);
      float hn = 1.0f - 2.0f * fast_rcp(ex + 1.0f);

      if (writer) {
        union { _Float16 h; unsigned short s; } cv;
        cv.h = (_Float16)hn;
        hs[(long)t * H_SZ] = cv.h;
        *(unsigned short*)&hraw[cur ^ 1][hwr_off] = cv.s;
        if (t == T_SZ - 1) hT[b * H_SZ + orow] = hn;
      }
      __syncthreads();
    }
#pragma unroll
    for (int j = 0; j < 8; ++j) xr[j] = xn[j];
  }
}

extern "C" void kernel_launch(void* const* d_in, const int* in_sizes, int n_in,
                              void* d_out, int out_size, void* d_ws,
                              size_t ws_size, hipStream_t stream) {
  const float* x = (const float*)d_in[0];
  const float* h0 = (const float*)d_in[1];
  const float* Wxh = (const float*)d_in[2];
  const float* Whh = (const float*)d_in[3];
  const float* bh = (const float*)d_in[4];
  const float* Wout = (const float*)d_in[5];
  const float* bout = (const float*)d_in[6];

  // d_out: [0, 64MB) first holds f16 Xp scratch, finally Y fp32;
  // hT tail at element offset B*T*O is beyond the Xp region.
  half_t* Xp = (half_t*)d_out;
  half_t* Hs = (half_t*)d_ws;  // 64 MB
  float* Y = (float*)d_out;
  float* hT = (float*)d_out + (long)B_SZ * T_SZ * O_SZ;

  const long M = (long)B_SZ * T_SZ;  // 131072

  // Phase A: Xp = f16(x @ Wxh^T + bh)   M x 256, K=128
  {
    dim3 grid((unsigned)(M / 128), H_SZ / 128);
    size_t sh = 2ull * 128 * 128 * sizeof(half_t);  // 64 KB
    hipLaunchKernelGGL((gemm_tn_bias<128, 128, 128, 128, false, true>), grid,
                       dim3(256), sh, stream, (const void*)x, Wxh, bh,
                       (void*)Xp, H_SZ);
  }
  // Phase B: sequential scan, one WG (8 waves) per batch chain
  hipLaunchKernelGGL(rnn_scan, dim3(B_SZ), dim3(512), 0, stream, Xp, Whh, h0,
                     Hs, hT);
  // Phase C: Y = Hs @ Wout^T + bout   M x 128, K=256
  {
    dim3 grid((unsigned)(M / 128), O_SZ / 128);
    size_t sh = 2ull * 128 * 128 * sizeof(half_t);  // 64 KB
    hipLaunchKernelGGL((gemm_tn_bias<128, 128, 128, 256, true, false>), grid,
                       dim3(256), sh, stream, (const void*)Hs, Wout, bout,
                       (void*)Y, O_SZ);
  }
}